// Round 7
// baseline (106.347 us; speedup 1.0000x reference)
//
#include <hip/hip_runtime.h>
#include <cstdint>
#include <cstddef>

constexpr int O_C   = 16;     // objects per image
constexpr int P_MAX = 8732;   // priors
constexpr int CH    = 4;      // match chunks per batch
constexpr int CHP   = 2183;   // priors per chunk (4*2183 = 8732)

struct f4u { float x, y, z, w; };   // 4-byte-aligned quad (rows are 324 B)

__device__ __forceinline__ float waveSumF(float v) {
    #pragma unroll
    for (int off = 32; off; off >>= 1) v += __shfl_xor(v, off);
    return v;
}
__device__ __forceinline__ int waveSumI(int v) {
    #pragma unroll
    for (int off = 32; off; off >>= 1) v += __shfl_xor(v, off);
    return v;
}

// ---------------------------------------------------------------------------
// K1 fused: blocks [0, nmatch) do per-batch-chunk matching;
//           blocks [nmatch, nmatch+nlse) do pure streaming LSE.
// The two halves are independent; match VALU work hides under LSE bandwidth.
// ---------------------------------------------------------------------------
__global__ __launch_bounds__(256, 4) void fused_stream(
    const float* __restrict__ confs,          // [rows,81]
    const float* __restrict__ target_boxes,   // [B,O,4] xyxy
    const float* __restrict__ priors,         // [P,4] cxcywh
    float* __restrict__ ov_out,               // [B,P]
    unsigned char* __restrict__ obj_out,      // [B,P]
    unsigned long long* __restrict__ okey_part, // [B*CH*O]
    float* __restrict__ lse_out,              // [rows]
    int P, int rows, int nmatch)
{
    const int tid  = threadIdx.x;

    if (blockIdx.x >= nmatch) {
        // ---------------- pure streaming LSE ----------------
        const int row = (blockIdx.x - nmatch) * 256 + tid;
        if (row >= rows) return;
        const float* rbase = confs + (size_t)row * 81;
        const f4u* rp = reinterpret_cast<const f4u*>(rbase);
        float m = -3.0e38f, s = 0.0f;
        #pragma unroll
        for (int j = 0; j < 20; ++j) {
            f4u a = rp[j];
            float m4 = fmaxf(fmaxf(a.x, a.y), fmaxf(a.z, a.w));
            float mn = fmaxf(m, m4);
            s = s * __expf(m - mn)
              + __expf(a.x - mn) + __expf(a.y - mn)
              + __expf(a.z - mn) + __expf(a.w - mn);
            m = mn;
        }
        {
            float last = rbase[80];
            float mn = fmaxf(m, last);
            s = s * __expf(m - mn) + __expf(last - mn);
            m = mn;
        }
        lse_out[row] = m + __logf(s);
        return;
    }

    // ---------------- matching chunk ----------------
    const int chunk = blockIdx.x;
    const int b    = chunk / CH;
    const int c    = chunk % CH;
    const int lane = tid & 63;
    const int wid  = tid >> 6;

    __shared__ float bx0[O_C], by0[O_C], bx1[O_C], by1[O_C], barea[O_C];
    __shared__ unsigned long long s_wb[O_C * 4];

    if (tid < O_C) {
        const float* tb = target_boxes + ((size_t)b * O_C + tid) * 4;
        float x0 = tb[0], y0 = tb[1], x1 = tb[2], y1 = tb[3];
        bx0[tid] = x0; by0[tid] = y0; bx1[tid] = x1; by1[tid] = y1;
        barea[tid] = (x1 - x0) * (y1 - y0);
    }
    __syncthreads();

    float bi[O_C]; int bp[O_C];
    #pragma unroll
    for (int o = 0; o < O_C; ++o) { bi[o] = -1.0f; bp[o] = 0; }

    const int p0 = c * CHP, p1 = min(p0 + CHP, P);
    for (int p = p0 + tid; p < p1; p += 256) {
        float4 pr = reinterpret_cast<const float4*>(priors)[p];
        float px0 = pr.x - pr.z * 0.5f, py0 = pr.y - pr.w * 0.5f;
        float px1 = pr.x + pr.z * 0.5f, py1 = pr.y + pr.w * 0.5f;
        float parea = (px1 - px0) * (py1 - py0);
        float bv = -1.0f; int bo = 0;
        #pragma unroll
        for (int o = 0; o < O_C; ++o) {
            float ix0 = fmaxf(px0, bx0[o]), iy0 = fmaxf(py0, by0[o]);
            float ix1 = fminf(px1, bx1[o]), iy1 = fminf(py1, by1[o]);
            float iw = fmaxf(ix1 - ix0, 0.0f), ih = fmaxf(iy1 - iy0, 0.0f);
            float inter = iw * ih;
            float iou = inter / (barea[o] + parea - inter);
            if (iou > bv) { bv = iou; bo = o; }          // first-max (argmax over o)
            if (iou > bi[o]) { bi[o] = iou; bp[o] = p; } // strict > -> smallest p
        }
        ov_out[(size_t)b * P + p]  = bv;
        obj_out[(size_t)b * P + p] = (unsigned char)bo;
    }

    // reduce per-object candidates: key = iou_bits<<32 | ~p (ties -> smaller p)
    #pragma unroll
    for (int o = 0; o < O_C; ++o) {
        unsigned long long k = (bi[o] >= 0.0f)
            ? (((unsigned long long)__float_as_uint(bi[o]) << 32) |
               (unsigned long long)(0xFFFFFFFFu - (unsigned)bp[o]))
            : 0ull;
        #pragma unroll
        for (int off = 32; off; off >>= 1) {
            unsigned long long k2 = __shfl_xor(k, off);
            if (k2 > k) k = k2;
        }
        if (lane == 0) s_wb[o * 4 + wid] = k;
    }
    __syncthreads();
    if (tid < O_C) {
        unsigned long long k = s_wb[tid * 4];
        #pragma unroll
        for (int w = 1; w < 4; ++w) if (s_wb[tid * 4 + w] > k) k = s_wb[tid * 4 + w];
        okey_part[(size_t)chunk * O_C + tid] = k;   // [b][c][o]
    }
}

// ---------------------------------------------------------------------------
// K2 hard: per-batch block. Computes labels (ov/obj + forced override),
// ce = lse - confs[row*81+l], pos sums / n_pos / loc loss, then exact
// top-K negative sum via radix select.
// ---------------------------------------------------------------------------
__global__ __launch_bounds__(1024) void hard_kernel(
    const float* __restrict__ confs,          // [rows,81]
    const float* __restrict__ lse,            // [rows]
    const float* __restrict__ ov_in,          // [B,P]
    const unsigned char* __restrict__ obj_in, // [B,P]
    const unsigned long long* __restrict__ okey_part, // [B*CH*O]
    const float* __restrict__ target_boxes,   // [B,O,4]
    const int*   __restrict__ target_labels,  // [B,O]
    const float* __restrict__ priors,         // [P,4]
    const float* __restrict__ predict_locs,   // [B,P,4]
    int*   __restrict__ n_pos,                // [B]
    float* __restrict__ ce_pos,               // [B]
    float* __restrict__ ce_hard,              // [B]
    float* __restrict__ loc_b,                // [B]
    int P)
{
    const int b    = blockIdx.x;
    const int tid  = threadIdx.x;
    const int lane = tid & 63;
    const int wid  = tid >> 6;

    __shared__ float s_v[P_MAX];
    __shared__ unsigned int hist[16][256];
    __shared__ float4 tbox[O_C];
    __shared__ int    tlab[O_C], topr[O_C];
    __shared__ unsigned int s_sel;
    __shared__ int s_kr;
    __shared__ float s_f[16], s_f2[16], s_f3[16];
    __shared__ int s_i[16];

    if (tid < O_C) {
        const float* tb = target_boxes + ((size_t)b * O_C + tid) * 4;
        tbox[tid] = make_float4(tb[0], tb[1], tb[2], tb[3]);
        tlab[tid] = target_labels[(size_t)b * O_C + tid];
        unsigned long long kk = 0ull;
        #pragma unroll
        for (int cc = 0; cc < CH; ++cc) {
            unsigned long long k2 = okey_part[((size_t)b * CH + cc) * O_C + tid];
            if (k2 > kk) kk = k2;
        }
        topr[tid] = (int)(0xFFFFFFFFu - (unsigned)(kk & 0xFFFFFFFFull));
    }
    __syncthreads();

    const size_t base = (size_t)b * P;
    float possum = 0.0f, negsum = 0.0f, locsum = 0.0f;
    int cnt = 0;
    for (int p = tid; p < P; p += 1024) {
        float ovv = ov_in[base + p];
        int   obj = obj_in[base + p];
        #pragma unroll
        for (int o = 0; o < O_C; ++o)            // ascending -> last write wins
            if (topr[o] == p) { obj = o; ovv = 1.0f; }
        const int l = (ovv < 0.5f) ? 0 : tlab[obj];
        float xl  = confs[(base + p) * 81 + l];
        float cev = lse[base + p] - xl;
        if (l != 0) {
            possum += cev; ++cnt;
            s_v[p] = 0.0f;
            float4 pr = reinterpret_cast<const float4*>(priors)[p];
            float4 tb = tbox[obj];
            float cx = (tb.x + tb.z) * 0.5f, cy = (tb.y + tb.w) * 0.5f;
            float w  = tb.z - tb.x,          h  = tb.w - tb.y;
            float g0 = (cx - pr.x) / (pr.z * 0.1f);
            float g1 = (cy - pr.y) / (pr.w * 0.1f);
            float g2 = logf(w / pr.z) / 0.2f;
            float g3 = logf(h / pr.w) / 0.2f;
            float4 pl = reinterpret_cast<const float4*>(predict_locs)[base + p];
            locsum += fabsf(pl.x - g0) + fabsf(pl.y - g1) +
                      fabsf(pl.z - g2) + fabsf(pl.w - g3);
        } else {
            negsum += cev;
            s_v[p] = cev;
        }
    }
    possum = waveSumF(possum);
    negsum = waveSumF(negsum);
    locsum = waveSumF(locsum);
    cnt    = waveSumI(cnt);
    if (lane == 0) { s_f[wid] = possum; s_f2[wid] = negsum; s_f3[wid] = locsum; s_i[wid] = cnt; }
    __syncthreads();
    float negsum_t = 0.0f, possum_t = 0.0f, locsum_t = 0.0f; int np = 0;
    #pragma unroll
    for (int w = 0; w < 16; ++w) {
        negsum_t += s_f2[w]; possum_t += s_f[w]; locsum_t += s_f3[w]; np += s_i[w];
    }
    if (tid == 0) { ce_pos[b] = possum_t; n_pos[b] = np; loc_b[b] = locsum_t; }

    const int K = 3 * np;
    if (K <= 0) { if (tid == 0) ce_hard[b] = 0.0f; return; }
    if (K >= P) { if (tid == 0) ce_hard[b] = negsum_t; return; }

    unsigned int prefix = 0; int kr = K;
    for (int shift = 24; shift >= 0; shift -= 8) {
        for (int i = tid; i < 16 * 256; i += 1024) (&hist[0][0])[i] = 0;
        __syncthreads();
        unsigned int maskHi = (shift == 24) ? 0u : (0xFFFFFFFFu << (shift + 8));
        for (int p = tid; p < P; p += 1024) {
            unsigned int u = __float_as_uint(s_v[p]);
            if ((u & maskHi) == prefix) atomicAdd(&hist[wid][(u >> shift) & 255], 1u);
        }
        __syncthreads();
        if (wid == 0) {
            unsigned h0 = 0, h1 = 0, h2 = 0, h3 = 0;
            #pragma unroll 4
            for (int w = 0; w < 16; ++w) {
                h0 += hist[w][lane * 4 + 0];
                h1 += hist[w][lane * 4 + 1];
                h2 += hist[w][lane * 4 + 2];
                h3 += hist[w][lane * 4 + 3];
            }
            unsigned own = h0 + h1 + h2 + h3;
            unsigned t = own;                    // inclusive suffix over lanes
            #pragma unroll
            for (int off = 1; off < 64; off <<= 1) {
                unsigned u = __shfl_down(t, off);
                if (lane + off >= 64) u = 0;
                t += u;
            }
            unsigned Tnext = t - own;            // strictly-higher lanes
            unsigned cum3 = Tnext;
            unsigned cum2 = cum3 + h3;
            unsigned cum1 = cum2 + h2;
            unsigned cum0 = cum1 + h1;
            unsigned kru = (unsigned)kr;
            int selj = -1; unsigned cg = 0;
            if      (cum3 < kru && kru <= cum3 + h3) { selj = 3; cg = cum3; }
            else if (cum2 < kru && kru <= cum2 + h2) { selj = 2; cg = cum2; }
            else if (cum1 < kru && kru <= cum1 + h1) { selj = 1; cg = cum1; }
            else if (cum0 < kru && kru <= cum0 + h0) { selj = 0; cg = cum0; }
            if (selj >= 0) {
                s_sel = prefix | ((unsigned)(lane * 4 + selj) << shift);
                s_kr  = kr - (int)cg;
            }
        }
        __syncthreads();
        prefix = s_sel; kr = s_kr;
        __syncthreads();
    }

    float sumgt = 0.0f;
    for (int p = tid; p < P; p += 1024) {
        unsigned int u = __float_as_uint(s_v[p]);
        if (u > prefix) sumgt += s_v[p];
    }
    sumgt = waveSumF(sumgt);
    if (lane == 0) s_f[wid] = sumgt;
    __syncthreads();
    if (tid == 0) {
        float sg = 0.0f;
        #pragma unroll
        for (int w = 0; w < 16; ++w) sg += s_f[w];
        ce_hard[b] = sg + (float)kr * __uint_as_float(prefix);
    }
}

// ---------------------------------------------------------------------------
// K3: finalize scalar loss. One wave, deterministic fixed-order sums.
// ---------------------------------------------------------------------------
__global__ __launch_bounds__(64) void finalize_kernel(
    const int*   __restrict__ n_pos,    // [B]
    const float* __restrict__ ce_pos,   // [B]
    const float* __restrict__ ce_hard,  // [B]
    const float* __restrict__ loc_b,    // [B]
    float* __restrict__ out, int B)
{
    const int lane = threadIdx.x;
    int np = 0; float cp = 0.0f, ch = 0.0f, la = 0.0f;
    for (int b = lane; b < B; b += 64) {
        np += n_pos[b]; cp += ce_pos[b]; ch += ce_hard[b]; la += loc_b[b];
    }
    #pragma unroll
    for (int off = 32; off; off >>= 1) {
        np += __shfl_xor(np, off);
        cp += __shfl_xor(cp, off);
        ch += __shfl_xor(ch, off);
        la += __shfl_xor(la, off);
    }
    if (lane == 0) {
        float npt = (float)np;
        out[0] = (ch + cp) / npt + la / (npt * 4.0f);
    }
}

extern "C" void kernel_launch(void* const* d_in, const int* in_sizes, int n_in,
                              void* d_out, int out_size, void* d_ws, size_t ws_size,
                              hipStream_t stream) {
    const float* predict_locs  = (const float*)d_in[0];
    const float* predict_confs = (const float*)d_in[1];
    const float* target_boxes  = (const float*)d_in[2];
    const int*   target_labels = (const int*)d_in[3];
    const float* priors        = (const float*)d_in[4];

    const int P = in_sizes[4] / 4;             // 8732
    const int B = in_sizes[0] / (P * 4);       // 64
    const int rows = B * P;                    // 558848
    const int nmatch = B * CH;                 // 256
    const int nlse = rows / 256;               // 2183 (rows % 256 == 0)

    char* ws = (char*)d_ws;
    unsigned long long* okey_part = (unsigned long long*)ws;
    ws += (size_t)nmatch * O_C * sizeof(unsigned long long);
    float* lse     = (float*)ws; ws += (size_t)rows * sizeof(float);
    float* ov      = (float*)ws; ws += (size_t)rows * sizeof(float);
    int*   n_pos   = (int*)ws;   ws += (size_t)B * sizeof(int);
    float* ce_pos  = (float*)ws; ws += (size_t)B * sizeof(float);
    float* ce_hard = (float*)ws; ws += (size_t)B * sizeof(float);
    float* loc_b   = (float*)ws; ws += (size_t)B * sizeof(float);
    unsigned char* obj = (unsigned char*)ws; ws += (size_t)rows;

    fused_stream<<<nmatch + nlse, 256, 0, stream>>>(
        predict_confs, target_boxes, priors, ov, obj, okey_part, lse,
        P, rows, nmatch);
    hard_kernel<<<B, 1024, 0, stream>>>(
        predict_confs, lse, ov, obj, okey_part, target_boxes, target_labels,
        priors, predict_locs, n_pos, ce_pos, ce_hard, loc_b, P);
    finalize_kernel<<<1, 64, 0, stream>>>(n_pos, ce_pos, ce_hard, loc_b,
                                          (float*)d_out, B);
}

// Round 8
// 94.723 us; speedup vs baseline: 1.1227x; 1.1227x over previous
//
#include <hip/hip_runtime.h>
#include <cstdint>
#include <cstddef>

constexpr int O_C   = 16;     // objects per image
constexpr int P_MAX = 8732;   // priors
constexpr int CH    = 4;      // match chunks per batch
constexpr int CHP   = 2183;   // priors per chunk (4*2183 = 8732)

__device__ __forceinline__ float waveSumF(float v) {
    #pragma unroll
    for (int off = 32; off; off >>= 1) v += __shfl_xor(v, off);
    return v;
}
__device__ __forceinline__ int waveSumI(int v) {
    #pragma unroll
    for (int off = 32; off; off >>= 1) v += __shfl_xor(v, off);
    return v;
}

// ---------------------------------------------------------------------------
// K1: blocks [0, nlse)        : pure LSE over 64-row tiles (coalesced stage)
//     blocks [nlse, nlse+256) : per-batch-chunk IoU matching
// ---------------------------------------------------------------------------
__global__ __launch_bounds__(256) void lse_match(
    const float* __restrict__ confs,          // [rows,81]
    const float* __restrict__ target_boxes,   // [B,O,4] xyxy
    const float* __restrict__ priors,         // [P,4] cxcywh
    float* __restrict__ ov_out,               // [B,P]
    unsigned char* __restrict__ obj_out,      // [B,P]
    unsigned long long* __restrict__ okey_part, // [B*CH*O]
    float* __restrict__ lse_out,              // [rows]
    int P, int nlse)
{
    const int tid  = threadIdx.x;
    const int lane = tid & 63;
    const int wid  = tid >> 6;

    __shared__ float s_x[64 * 81 + 4];        // +4 pad for speculative reads
    __shared__ float bx0[O_C], by0[O_C], bx1[O_C], by1[O_C], barea[O_C];
    __shared__ unsigned long long s_wb[O_C * 4];

    if (blockIdx.x < (unsigned)nlse) {
        // ---------------- pure tile LSE ----------------
        const size_t tbase = (size_t)blockIdx.x * 64 * 81;   // floats
        {
            const float4* src = reinterpret_cast<const float4*>(confs + tbase);
            float4* dst = reinterpret_cast<float4*>(s_x);
            #pragma unroll
            for (int k = 0; k < 6; ++k) {
                int i = tid + k * 256;
                if (i < 1296) dst[i] = src[i];   // 1296 = 64*81/4, coalesced
            }
        }
        __syncthreads();

        const int rl = tid >> 2;                  // local row 0..63
        const int q  = tid & 3;
        const int s0 = q ? (q * 20 + 1) : 0;      // 0,21,41,61
        const int n  = q ? 20 : 21;
        const float* xr = s_x + rl * 81;

        float v[21];
        #pragma unroll
        for (int i = 0; i < 21; ++i)
            v[i] = (i < n) ? xr[s0 + i] : -3.0e38f;

        float m = v[0];
        #pragma unroll
        for (int i = 1; i < 21; ++i) m = fmaxf(m, v[i]);
        m = fmaxf(m, __shfl_xor(m, 1));
        m = fmaxf(m, __shfl_xor(m, 2));

        float s = 0.0f;
        #pragma unroll
        for (int i = 0; i < 21; ++i)
            if (i < n) s += __expf(v[i] - m);
        s += __shfl_xor(s, 1);
        s += __shfl_xor(s, 2);

        if (q == 0)
            lse_out[(size_t)blockIdx.x * 64 + rl] = m + __logf(s);
        return;
    }

    // ---------------- matching chunk ----------------
    const int chunk = blockIdx.x - nlse;
    const int b = chunk / CH;
    const int c = chunk % CH;

    if (tid < O_C) {
        const float* tb = target_boxes + ((size_t)b * O_C + tid) * 4;
        float x0 = tb[0], y0 = tb[1], x1 = tb[2], y1 = tb[3];
        bx0[tid] = x0; by0[tid] = y0; bx1[tid] = x1; by1[tid] = y1;
        barea[tid] = (x1 - x0) * (y1 - y0);
    }
    __syncthreads();

    float bi[O_C]; int bp[O_C];
    #pragma unroll
    for (int o = 0; o < O_C; ++o) { bi[o] = -1.0f; bp[o] = 0; }

    const int p0 = c * CHP, p1 = min(p0 + CHP, P);
    for (int p = p0 + tid; p < p1; p += 256) {
        float4 pr = reinterpret_cast<const float4*>(priors)[p];
        float px0 = pr.x - pr.z * 0.5f, py0 = pr.y - pr.w * 0.5f;
        float px1 = pr.x + pr.z * 0.5f, py1 = pr.y + pr.w * 0.5f;
        float parea = (px1 - px0) * (py1 - py0);
        float bv = -1.0f; int bo = 0;
        #pragma unroll
        for (int o = 0; o < O_C; ++o) {
            float ix0 = fmaxf(px0, bx0[o]), iy0 = fmaxf(py0, by0[o]);
            float ix1 = fminf(px1, bx1[o]), iy1 = fminf(py1, by1[o]);
            float iw = fmaxf(ix1 - ix0, 0.0f), ih = fmaxf(iy1 - iy0, 0.0f);
            float inter = iw * ih;
            float iou = inter / (barea[o] + parea - inter);
            if (iou > bv) { bv = iou; bo = o; }          // first-max (argmax over o)
            if (iou > bi[o]) { bi[o] = iou; bp[o] = p; } // strict > -> smallest p
        }
        ov_out[(size_t)b * P + p]  = bv;
        obj_out[(size_t)b * P + p] = (unsigned char)bo;
    }

    // reduce per-object candidates: key = iou_bits<<32 | ~p (ties -> smaller p)
    #pragma unroll
    for (int o = 0; o < O_C; ++o) {
        unsigned long long k = (bi[o] >= 0.0f)
            ? (((unsigned long long)__float_as_uint(bi[o]) << 32) |
               (unsigned long long)(0xFFFFFFFFu - (unsigned)bp[o]))
            : 0ull;
        #pragma unroll
        for (int off = 32; off; off >>= 1) {
            unsigned long long k2 = __shfl_xor(k, off);
            if (k2 > k) k = k2;
        }
        if (lane == 0) s_wb[o * 4 + wid] = k;
    }
    __syncthreads();
    if (tid < O_C) {
        unsigned long long k = s_wb[tid * 4];
        #pragma unroll
        for (int w = 1; w < 4; ++w) if (s_wb[tid * 4 + w] > k) k = s_wb[tid * 4 + w];
        okey_part[(size_t)chunk * O_C + tid] = k;   // [b][c][o]
    }
}

// ---------------------------------------------------------------------------
// K2 hard: per-batch block. Labels (ov/obj + forced override),
// ce = lse - confs[row*81+l], pos sums / n_pos / loc loss, then exact
// top-K negative sum via radix select.
// ---------------------------------------------------------------------------
__global__ __launch_bounds__(1024) void hard_kernel(
    const float* __restrict__ confs,          // [rows,81]
    const float* __restrict__ lse,            // [rows]
    const float* __restrict__ ov_in,          // [B,P]
    const unsigned char* __restrict__ obj_in, // [B,P]
    const unsigned long long* __restrict__ okey_part, // [B*CH*O]
    const float* __restrict__ target_boxes,   // [B,O,4]
    const int*   __restrict__ target_labels,  // [B,O]
    const float* __restrict__ priors,         // [P,4]
    const float* __restrict__ predict_locs,   // [B,P,4]
    int*   __restrict__ n_pos,                // [B]
    float* __restrict__ ce_pos,               // [B]
    float* __restrict__ ce_hard,              // [B]
    float* __restrict__ loc_b,                // [B]
    int P)
{
    const int b    = blockIdx.x;
    const int tid  = threadIdx.x;
    const int lane = tid & 63;
    const int wid  = tid >> 6;

    __shared__ float s_v[P_MAX];
    __shared__ unsigned int hist[16][256];
    __shared__ float4 tbox[O_C];
    __shared__ int    tlab[O_C], topr[O_C];
    __shared__ unsigned int s_sel;
    __shared__ int s_kr;
    __shared__ float s_f[16], s_f2[16], s_f3[16];
    __shared__ int s_i[16];

    if (tid < O_C) {
        const float* tb = target_boxes + ((size_t)b * O_C + tid) * 4;
        tbox[tid] = make_float4(tb[0], tb[1], tb[2], tb[3]);
        tlab[tid] = target_labels[(size_t)b * O_C + tid];
        unsigned long long kk = 0ull;
        #pragma unroll
        for (int cc = 0; cc < CH; ++cc) {
            unsigned long long k2 = okey_part[((size_t)b * CH + cc) * O_C + tid];
            if (k2 > kk) kk = k2;
        }
        topr[tid] = (int)(0xFFFFFFFFu - (unsigned)(kk & 0xFFFFFFFFull));
    }
    __syncthreads();

    const size_t base = (size_t)b * P;
    float possum = 0.0f, negsum = 0.0f, locsum = 0.0f;
    int cnt = 0;
    for (int p = tid; p < P; p += 1024) {
        float ovv = ov_in[base + p];
        int   obj = obj_in[base + p];
        #pragma unroll
        for (int o = 0; o < O_C; ++o)            // ascending -> last write wins
            if (topr[o] == p) { obj = o; ovv = 1.0f; }
        const int l = (ovv < 0.5f) ? 0 : tlab[obj];
        float xl  = confs[(base + p) * 81 + l];
        float cev = lse[base + p] - xl;
        if (l != 0) {
            possum += cev; ++cnt;
            s_v[p] = 0.0f;
            float4 pr = reinterpret_cast<const float4*>(priors)[p];
            float4 tb = tbox[obj];
            float cx = (tb.x + tb.z) * 0.5f, cy = (tb.y + tb.w) * 0.5f;
            float w  = tb.z - tb.x,          h  = tb.w - tb.y;
            float g0 = (cx - pr.x) / (pr.z * 0.1f);
            float g1 = (cy - pr.y) / (pr.w * 0.1f);
            float g2 = logf(w / pr.z) / 0.2f;
            float g3 = logf(h / pr.w) / 0.2f;
            float4 pl = reinterpret_cast<const float4*>(predict_locs)[base + p];
            locsum += fabsf(pl.x - g0) + fabsf(pl.y - g1) +
                      fabsf(pl.z - g2) + fabsf(pl.w - g3);
        } else {
            negsum += cev;
            s_v[p] = cev;
        }
    }
    possum = waveSumF(possum);
    negsum = waveSumF(negsum);
    locsum = waveSumF(locsum);
    cnt    = waveSumI(cnt);
    if (lane == 0) { s_f[wid] = possum; s_f2[wid] = negsum; s_f3[wid] = locsum; s_i[wid] = cnt; }
    __syncthreads();
    float negsum_t = 0.0f, possum_t = 0.0f, locsum_t = 0.0f; int np = 0;
    #pragma unroll
    for (int w = 0; w < 16; ++w) {
        negsum_t += s_f2[w]; possum_t += s_f[w]; locsum_t += s_f3[w]; np += s_i[w];
    }
    if (tid == 0) { ce_pos[b] = possum_t; n_pos[b] = np; loc_b[b] = locsum_t; }

    const int K = 3 * np;
    if (K <= 0) { if (tid == 0) ce_hard[b] = 0.0f; return; }
    if (K >= P) { if (tid == 0) ce_hard[b] = negsum_t; return; }

    unsigned int prefix = 0; int kr = K;
    for (int shift = 24; shift >= 0; shift -= 8) {
        for (int i = tid; i < 16 * 256; i += 1024) (&hist[0][0])[i] = 0;
        __syncthreads();
        unsigned int maskHi = (shift == 24) ? 0u : (0xFFFFFFFFu << (shift + 8));
        for (int p = tid; p < P; p += 1024) {
            unsigned int u = __float_as_uint(s_v[p]);
            if ((u & maskHi) == prefix) atomicAdd(&hist[wid][(u >> shift) & 255], 1u);
        }
        __syncthreads();
        if (wid == 0) {
            unsigned h0 = 0, h1 = 0, h2 = 0, h3 = 0;
            #pragma unroll 4
            for (int w = 0; w < 16; ++w) {
                h0 += hist[w][lane * 4 + 0];
                h1 += hist[w][lane * 4 + 1];
                h2 += hist[w][lane * 4 + 2];
                h3 += hist[w][lane * 4 + 3];
            }
            unsigned own = h0 + h1 + h2 + h3;
            unsigned t = own;                    // inclusive suffix over lanes
            #pragma unroll
            for (int off = 1; off < 64; off <<= 1) {
                unsigned u = __shfl_down(t, off);
                if (lane + off >= 64) u = 0;
                t += u;
            }
            unsigned Tnext = t - own;            // strictly-higher lanes
            unsigned cum3 = Tnext;
            unsigned cum2 = cum3 + h3;
            unsigned cum1 = cum2 + h2;
            unsigned cum0 = cum1 + h1;
            unsigned kru = (unsigned)kr;
            int selj = -1; unsigned cg = 0;
            if      (cum3 < kru && kru <= cum3 + h3) { selj = 3; cg = cum3; }
            else if (cum2 < kru && kru <= cum2 + h2) { selj = 2; cg = cum2; }
            else if (cum1 < kru && kru <= cum1 + h1) { selj = 1; cg = cum1; }
            else if (cum0 < kru && kru <= cum0 + h0) { selj = 0; cg = cum0; }
            if (selj >= 0) {
                s_sel = prefix | ((unsigned)(lane * 4 + selj) << shift);
                s_kr  = kr - (int)cg;
            }
        }
        __syncthreads();
        prefix = s_sel; kr = s_kr;
        __syncthreads();
    }

    float sumgt = 0.0f;
    for (int p = tid; p < P; p += 1024) {
        unsigned int u = __float_as_uint(s_v[p]);
        if (u > prefix) sumgt += s_v[p];
    }
    sumgt = waveSumF(sumgt);
    if (lane == 0) s_f[wid] = sumgt;
    __syncthreads();
    if (tid == 0) {
        float sg = 0.0f;
        #pragma unroll
        for (int w = 0; w < 16; ++w) sg += s_f[w];
        ce_hard[b] = sg + (float)kr * __uint_as_float(prefix);
    }
}

// ---------------------------------------------------------------------------
// K3: finalize scalar loss. One wave, deterministic fixed-order sums.
// ---------------------------------------------------------------------------
__global__ __launch_bounds__(64) void finalize_kernel(
    const int*   __restrict__ n_pos,    // [B]
    const float* __restrict__ ce_pos,   // [B]
    const float* __restrict__ ce_hard,  // [B]
    const float* __restrict__ loc_b,    // [B]
    float* __restrict__ out, int B)
{
    const int lane = threadIdx.x;
    int np = 0; float cp = 0.0f, ch = 0.0f, la = 0.0f;
    for (int b = lane; b < B; b += 64) {
        np += n_pos[b]; cp += ce_pos[b]; ch += ce_hard[b]; la += loc_b[b];
    }
    #pragma unroll
    for (int off = 32; off; off >>= 1) {
        np += __shfl_xor(np, off);
        cp += __shfl_xor(cp, off);
        ch += __shfl_xor(ch, off);
        la += __shfl_xor(la, off);
    }
    if (lane == 0) {
        float npt = (float)np;
        out[0] = (ch + cp) / npt + la / (npt * 4.0f);
    }
}

extern "C" void kernel_launch(void* const* d_in, const int* in_sizes, int n_in,
                              void* d_out, int out_size, void* d_ws, size_t ws_size,
                              hipStream_t stream) {
    const float* predict_locs  = (const float*)d_in[0];
    const float* predict_confs = (const float*)d_in[1];
    const float* target_boxes  = (const float*)d_in[2];
    const int*   target_labels = (const int*)d_in[3];
    const float* priors        = (const float*)d_in[4];

    const int P = in_sizes[4] / 4;             // 8732
    const int B = in_sizes[0] / (P * 4);       // 64
    const int rows = B * P;                    // 558848
    const int nmatch = B * CH;                 // 256
    const int nlse = rows / 64;                // 8732 (rows % 64 == 0)

    char* ws = (char*)d_ws;
    unsigned long long* okey_part = (unsigned long long*)ws;
    ws += (size_t)nmatch * O_C * sizeof(unsigned long long);
    float* lse     = (float*)ws; ws += (size_t)rows * sizeof(float);
    float* ov      = (float*)ws; ws += (size_t)rows * sizeof(float);
    int*   n_pos   = (int*)ws;   ws += (size_t)B * sizeof(int);
    float* ce_pos  = (float*)ws; ws += (size_t)B * sizeof(float);
    float* ce_hard = (float*)ws; ws += (size_t)B * sizeof(float);
    float* loc_b   = (float*)ws; ws += (size_t)B * sizeof(float);
    unsigned char* obj = (unsigned char*)ws; ws += (size_t)rows;

    lse_match<<<nlse + nmatch, 256, 0, stream>>>(
        predict_confs, target_boxes, priors, ov, obj, okey_part, lse, P, nlse);
    hard_kernel<<<B, 1024, 0, stream>>>(
        predict_confs, lse, ov, obj, okey_part, target_boxes, target_labels,
        priors, predict_locs, n_pos, ce_pos, ce_hard, loc_b, P);
    finalize_kernel<<<1, 64, 0, stream>>>(n_pos, ce_pos, ce_hard, loc_b,
                                          (float*)d_out, B);
}